// Round 2
// baseline (716.294 us; speedup 1.0000x reference)
//
#include <hip/hip_runtime.h>

typedef short bf16x8 __attribute__((ext_vector_type(8)));
typedef float f32x4 __attribute__((ext_vector_type(4)));

#define MFMA16(a, b, c) __builtin_amdgcn_mfma_f32_16x16x32_bf16((a), (b), (c), 0, 0, 0)

static constexpr int T_LEN = 512;
static constexpr int F_DIM = 64;
static constexpr int NB    = 16;   // batch rows per block

__device__ __forceinline__ float fast_tanh(float z) {
  float e = __expf(2.0f * z);
  return 1.0f - 2.0f / (e + 1.0f);
}

// split fp32 v into hi/lo bf16 bit patterns (truncation; lo captures next 8 bits)
__device__ __forceinline__ void split1(float v, unsigned short &h, unsigned short &l) {
  unsigned u  = __float_as_uint(v);
  unsigned uh = u & 0xffff0000u;
  h = (unsigned short)(u >> 16);
  float rem = v - __uint_as_float(uh);
  l = (unsigned short)(__float_as_uint(rem) >> 16);
}

__device__ __forceinline__ void split8(const float4 &a, const float4 &b,
                                       bf16x8 &h8, bf16x8 &l8) {
  float v[8] = {a.x, a.y, a.z, a.w, b.x, b.y, b.z, b.w};
#pragma unroll
  for (int i = 0; i < 8; ++i) {
    unsigned short h, l;
    split1(v[i], h, l);
    h8[i] = (short)h;
    l8[i] = (short)l;
  }
}

// One full RNN step (m-cell then p-cell) for this block's 16 batch rows.
// cur buffers (_c) receive new state; prev buffers (_p) hold old state.
template<bool FIN>
__device__ __forceinline__ void step_cells(
    int l15, int g, int j,
    const bf16x8 &xh0, const bf16x8 &xl0, const bf16x8 &xh1, const bf16x8 &xl1,
    const bf16x8 (&BmH)[6], const bf16x8 (&BmL)[6],
    const bf16x8 (&BpH)[6], const bf16x8 (&BpL)[6],
    float bias_m, float bias_p,
    unsigned short (*smh_c)[72], unsigned short (*sml_c)[72],
    unsigned short (*smh_p)[72], unsigned short (*sml_p)[72],
    unsigned short (*sph_c)[72], unsigned short (*spl_c)[72],
    unsigned short (*sph_p)[72], unsigned short (*spl_p)[72],
    float (*mfin)[68], float (*pfin)[68])
{
  const int g8 = g * 8;
  // p_old fragments (reused by both cells; buffer not rewritten this step)
  bf16x8 ph0 = *(const bf16x8 *)&sph_p[l15][g8];
  bf16x8 pl0 = *(const bf16x8 *)&spl_p[l15][g8];
  bf16x8 ph1 = *(const bf16x8 *)&sph_p[l15][32 + g8];
  bf16x8 pl1 = *(const bf16x8 *)&spl_p[l15][32 + g8];

  // ---------------- metrics cell: in = [x | p_old | m_old]
  {
    bf16x8 mh0 = *(const bf16x8 *)&smh_p[l15][g8];
    bf16x8 ml0 = *(const bf16x8 *)&sml_p[l15][g8];
    bf16x8 mh1 = *(const bf16x8 *)&smh_p[l15][32 + g8];
    bf16x8 ml1 = *(const bf16x8 *)&sml_p[l15][32 + g8];
    f32x4 a0 = {bias_m, bias_m, bias_m, bias_m};
    f32x4 a1 = {0.f, 0.f, 0.f, 0.f};
    f32x4 a2 = {0.f, 0.f, 0.f, 0.f};
    f32x4 a3 = {0.f, 0.f, 0.f, 0.f};
    a0 = MFMA16(xh0, BmH[0], a0);
    a1 = MFMA16(xl0, BmH[0], a1);
    a2 = MFMA16(xh0, BmL[0], a2);
    a3 = MFMA16(xh1, BmH[1], a3);
    a0 = MFMA16(xl1, BmH[1], a0);
    a1 = MFMA16(xh1, BmL[1], a1);
    a2 = MFMA16(ph0, BmH[2], a2);
    a3 = MFMA16(pl0, BmH[2], a3);
    a0 = MFMA16(ph0, BmL[2], a0);
    a1 = MFMA16(ph1, BmH[3], a1);
    a2 = MFMA16(pl1, BmH[3], a2);
    a3 = MFMA16(ph1, BmL[3], a3);
    a0 = MFMA16(mh0, BmH[4], a0);
    a1 = MFMA16(ml0, BmH[4], a1);
    a2 = MFMA16(mh0, BmL[4], a2);
    a3 = MFMA16(mh1, BmH[5], a3);
    a0 = MFMA16(ml1, BmH[5], a0);
    a1 = MFMA16(mh1, BmL[5], a1);
#pragma unroll
    for (int r = 0; r < 4; ++r) {
      float z  = (a0[r] + a1[r]) + (a2[r] + a3[r]);
      float tv = fast_tanh(z);
      unsigned short h, l;
      split1(tv, h, l);
      const int brow = g * 4 + r;
      smh_c[brow][j] = h;
      sml_c[brow][j] = l;
      if (FIN) mfin[brow][j] = tv;
    }
  }
  __syncthreads();   // m_new visible to all waves
  // ---------------- price cell: in = [x | m_new | p_old]
  {
    bf16x8 nh0 = *(const bf16x8 *)&smh_c[l15][g8];
    bf16x8 nl0 = *(const bf16x8 *)&sml_c[l15][g8];
    bf16x8 nh1 = *(const bf16x8 *)&smh_c[l15][32 + g8];
    bf16x8 nl1 = *(const bf16x8 *)&sml_c[l15][32 + g8];
    f32x4 a0 = {bias_p, bias_p, bias_p, bias_p};
    f32x4 a1 = {0.f, 0.f, 0.f, 0.f};
    f32x4 a2 = {0.f, 0.f, 0.f, 0.f};
    f32x4 a3 = {0.f, 0.f, 0.f, 0.f};
    a0 = MFMA16(xh0, BpH[0], a0);
    a1 = MFMA16(xl0, BpH[0], a1);
    a2 = MFMA16(xh0, BpL[0], a2);
    a3 = MFMA16(xh1, BpH[1], a3);
    a0 = MFMA16(xl1, BpH[1], a0);
    a1 = MFMA16(xh1, BpL[1], a1);
    a2 = MFMA16(nh0, BpH[2], a2);
    a3 = MFMA16(nl0, BpH[2], a3);
    a0 = MFMA16(nh0, BpL[2], a0);
    a1 = MFMA16(nh1, BpH[3], a1);
    a2 = MFMA16(nl1, BpH[3], a2);
    a3 = MFMA16(nh1, BpL[3], a3);   // FIXED: was BpH[3] (duplicated hi·hi, omitted hi·lo)
    a0 = MFMA16(ph0, BpH[4], a0);
    a1 = MFMA16(pl0, BpH[4], a1);
    a2 = MFMA16(ph0, BpL[4], a2);
    a3 = MFMA16(ph1, BpH[5], a3);
    a0 = MFMA16(pl1, BpH[5], a0);
    a1 = MFMA16(ph1, BpL[5], a1);
#pragma unroll
    for (int r = 0; r < 4; ++r) {
      float z  = (a0[r] + a1[r]) + (a2[r] + a3[r]);
      float tv = fast_tanh(z);
      unsigned short h, l;
      split1(tv, h, l);
      const int brow = g * 4 + r;
      sph_c[brow][j] = h;
      spl_c[brow][j] = l;
      if (FIN) pfin[brow][j] = tv;
    }
  }
  __syncthreads();   // p_new visible; prev buffers free for overwrite next step
}

__global__ __launch_bounds__(256, 1)
void mr_rnn_kernel(const float *__restrict__ x,
                   const float *__restrict__ mWih, const float *__restrict__ mWhh,
                   const float *__restrict__ mbih, const float *__restrict__ mbhh,
                   const float *__restrict__ pWih, const float *__restrict__ pWhh,
                   const float *__restrict__ pbih, const float *__restrict__ pbhh,
                   const float *__restrict__ plW,  const float *__restrict__ plb,
                   const float *__restrict__ mlW,  const float *__restrict__ mlb,
                   float *__restrict__ out, int B)
{
  __shared__ __align__(16) unsigned short sm_hi[2][NB][72], sm_lo[2][NB][72];
  __shared__ __align__(16) unsigned short sp_hi[2][NB][72], sp_lo[2][NB][72];
  __shared__ __align__(16) float s_mfin[NB][68], s_pfin[NB][68];

  const int tid  = threadIdx.x;
  const int lane = tid & 63;
  const int q    = tid >> 6;       // wave id 0..3 -> output col tile
  const int l15  = lane & 15;      // A-row (batch) / B-col (j) within tile
  const int g    = lane >> 4;      // k-group
  const int j    = q * 16 + l15;   // output feature owned by this lane's wave
  const int b0   = blockIdx.x * NB;
  const int g8   = g * 8;

  // ---- build register-resident weight B-fragments: B[k][j] = W[j][k], hi/lo bf16
  bf16x8 BmH[6], BmL[6], BpH[6], BpL[6];
#pragma unroll
  for (int kt = 0; kt < 6; ++kt) {
    const int k0 = kt * 32 + g8;
#pragma unroll
    for (int i = 0; i < 8; ++i) {
      const int k = k0 + i;
      float wm = (k < 128) ? mWih[j * 128 + k] : mWhh[j * 64 + (k - 128)];
      float wp = (k < 128) ? pWih[j * 128 + k] : pWhh[j * 64 + (k - 128)];
      unsigned short h, l;
      split1(wm, h, l);
      BmH[kt][i] = (short)h; BmL[kt][i] = (short)l;
      split1(wp, h, l);
      BpH[kt][i] = (short)h; BpL[kt][i] = (short)l;
    }
  }
  const float bias_m = mbih[j] + mbhh[j];
  const float bias_p = pbih[j] + pbhh[j];

  // ---- zero the t=-1 state buffers (parity index 1)
  for (int idx = tid; idx < NB * 72; idx += 256) {
    const int bb = idx / 72, kk = idx % 72;
    sm_hi[1][bb][kk] = 0; sm_lo[1][bb][kk] = 0;
    sp_hi[1][bb][kk] = 0; sp_lo[1][bb][kk] = 0;
  }

  // ---- x stream: this lane covers batch b0+l15, features [g8,g8+8) and [32+g8,32+g8+8)
  const float *xrow = x + (size_t)(b0 + l15) * T_LEN * F_DIM;
  float4 A0, A1, A2, A3, C0, C1, C2, C3;
  A0 = *(const float4 *)(xrow + 0 * F_DIM + g8);
  A1 = *(const float4 *)(xrow + 0 * F_DIM + g8 + 4);
  A2 = *(const float4 *)(xrow + 0 * F_DIM + 32 + g8);
  A3 = *(const float4 *)(xrow + 0 * F_DIM + 32 + g8 + 4);
  C0 = *(const float4 *)(xrow + 1 * F_DIM + g8);
  C1 = *(const float4 *)(xrow + 1 * F_DIM + g8 + 4);
  C2 = *(const float4 *)(xrow + 1 * F_DIM + 32 + g8);
  C3 = *(const float4 *)(xrow + 1 * F_DIM + 32 + g8 + 4);
  bf16x8 xh0, xl0, xh1, xl1;
  split8(A0, A1, xh0, xl0);
  split8(A2, A3, xh1, xl1);
  __syncthreads();   // zero-init visible

#pragma unroll 1
  for (int t = 0; t < T_LEN - 2; t += 2) {
    // ---- step t (even): cur=0, prev=1; prefetch x(t+2) into A*
    A0 = *(const float4 *)(xrow + (size_t)(t + 2) * F_DIM + g8);
    A1 = *(const float4 *)(xrow + (size_t)(t + 2) * F_DIM + g8 + 4);
    A2 = *(const float4 *)(xrow + (size_t)(t + 2) * F_DIM + 32 + g8);
    A3 = *(const float4 *)(xrow + (size_t)(t + 2) * F_DIM + 32 + g8 + 4);
    step_cells<false>(l15, g, j, xh0, xl0, xh1, xl1, BmH, BmL, BpH, BpL,
                      bias_m, bias_p,
                      sm_hi[0], sm_lo[0], sm_hi[1], sm_lo[1],
                      sp_hi[0], sp_lo[0], sp_hi[1], sp_lo[1],
                      s_mfin, s_pfin);
    split8(C0, C1, xh0, xl0);
    split8(C2, C3, xh1, xl1);
    // ---- step t+1 (odd): cur=1, prev=0; prefetch x(t+3) into C*
    C0 = *(const float4 *)(xrow + (size_t)(t + 3) * F_DIM + g8);
    C1 = *(const float4 *)(xrow + (size_t)(t + 3) * F_DIM + g8 + 4);
    C2 = *(const float4 *)(xrow + (size_t)(t + 3) * F_DIM + 32 + g8);
    C3 = *(const float4 *)(xrow + (size_t)(t + 3) * F_DIM + 32 + g8 + 4);
    step_cells<false>(l15, g, j, xh0, xl0, xh1, xl1, BmH, BmL, BpH, BpL,
                      bias_m, bias_p,
                      sm_hi[1], sm_lo[1], sm_hi[0], sm_lo[0],
                      sp_hi[1], sp_lo[1], sp_hi[0], sp_lo[0],
                      s_mfin, s_pfin);
    split8(A0, A1, xh0, xl0);
    split8(A2, A3, xh1, xl1);
  }
  // ---- step 510: cur=0, prev=1
  step_cells<false>(l15, g, j, xh0, xl0, xh1, xl1, BmH, BmL, BpH, BpL,
                    bias_m, bias_p,
                    sm_hi[0], sm_lo[0], sm_hi[1], sm_lo[1],
                    sp_hi[0], sp_lo[0], sp_hi[1], sp_lo[1],
                    s_mfin, s_pfin);
  split8(C0, C1, xh0, xl0);
  split8(C2, C3, xh1, xl1);
  // ---- step 511: cur=1, prev=0 (writes fp32 finals)
  step_cells<true>(l15, g, j, xh0, xl0, xh1, xl1, BmH, BmL, BpH, BpL,
                   bias_m, bias_p,
                   sm_hi[1], sm_lo[1], sm_hi[0], sm_lo[0],
                   sp_hi[1], sp_lo[1], sp_hi[0], sp_lo[0],
                   s_mfin, s_pfin);

  // ---- heads (trailing __syncthreads inside step_cells orders s_*fin)
  if (tid < NB) {
    const int b = tid;
    float acc = plb[0];
#pragma unroll 1
    for (int k = 0; k < 64; ++k) acc += s_pfin[b][k] * plW[k];
    out[b0 + b] = acc;
  } else if (tid < NB + NB * 8) {
    const int r = tid - NB;
    const int b = r >> 3, e = r & 7;
    float acc = mlb[e];
#pragma unroll 1
    for (int k = 0; k < 64; ++k) acc += s_mfin[b][k] * mlW[e * 64 + k];
    out[(size_t)B + (size_t)(b0 + b) * 8 + e] = acc;
  }
}

extern "C" void kernel_launch(void* const* d_in, const int* in_sizes, int n_in,
                              void* d_out, int out_size, void* d_ws, size_t ws_size,
                              hipStream_t stream) {
  (void)n_in; (void)out_size; (void)d_ws; (void)ws_size;
  const float* x    = (const float*)d_in[0];
  const float* mWih = (const float*)d_in[1];
  const float* mWhh = (const float*)d_in[2];
  const float* mbih = (const float*)d_in[3];
  const float* mbhh = (const float*)d_in[4];
  const float* pWih = (const float*)d_in[5];
  const float* pWhh = (const float*)d_in[6];
  const float* pbih = (const float*)d_in[7];
  const float* pbhh = (const float*)d_in[8];
  const float* plW  = (const float*)d_in[9];
  const float* plb  = (const float*)d_in[10];
  const float* mlW  = (const float*)d_in[11];
  const float* mlb  = (const float*)d_in[12];
  const int B = in_sizes[0] / (T_LEN * F_DIM);
  const int nblk = B / NB;
  mr_rnn_kernel<<<dim3(nblk), dim3(256), 0, stream>>>(
      x, mWih, mWhh, mbih, mbhh, pWih, pWhh, pbih, pbhh,
      plW, plb, mlW, mlb, (float*)d_out, B);
}